// Round 4
// baseline (260.923 us; speedup 1.0000x reference)
//
#include <hip/hip_runtime.h>
#include <hip/hip_bf16.h>

#define N_NODES 65536
#define N_EDGES 1048576
#define F_IN    128
#define HEADS   4
#define HID     64
#define NHID    256   // HEADS*HID
#define NEG     0.2f
#define NBUCK   1024  // coarse buckets = dst>>6
#define BCAP    2048  // slots per bucket (expected 1024, overflow impossible in practice)

typedef float fx4 __attribute__((ext_vector_type(4)));
typedef short bf16x8 __attribute__((ext_vector_type(8)));
typedef float f32x4 __attribute__((ext_vector_type(4)));
typedef float f32x2 __attribute__((ext_vector_type(2)));

__device__ inline unsigned short f2bf(float f) {
    unsigned u = __float_as_uint(f);
    u += 0x7fff + ((u >> 16) & 1);          // round-to-nearest-even
    return (unsigned short)(u >> 16);
}
__device__ inline float bf2f(unsigned short h) {
    return __uint_as_float((unsigned)h << 16);
}
__device__ inline f32x2 upk(unsigned w) {
    f32x2 r;
    r.x = __uint_as_float(w << 16);
    r.y = __uint_as_float(w & 0xffff0000u);
    return r;
}

// ---------------------------------------------------------------- BN stats + x -> bf16 hi/lo (pre-swizzled)
// swizzle: within each 256B row, 16B slot s stored at slot s ^ (row&7)
__global__ __launch_bounds__(256) void k_bn_stats(const float* __restrict__ x,
                                                  float* __restrict__ sums,
                                                  unsigned short* __restrict__ xhi,
                                                  unsigned short* __restrict__ xlo) {
    const int t = threadIdx.x;
    const int lane = t & 63;
    const int w = t >> 6;
    const int wid = blockIdx.x * 4 + w;            // 0..1023 global wave id
    float s0 = 0.f, s1 = 0.f, q0 = 0.f, q1 = 0.f;
    for (int i = 0; i < 64; ++i) {
        int r = wid + i * 1024;
        float2 v = *(const float2*)(x + (size_t)r * F_IN + lane * 2);
        s0 += v.x; q0 += v.x * v.x;
        s1 += v.y; q1 += v.y * v.y;
        unsigned short h0 = f2bf(v.x), h1 = f2bf(v.y);
        unsigned short l0 = f2bf(v.x - bf2f(h0)), l1 = f2bf(v.y - bf2f(h1));
        int slot = (lane >> 2) ^ (r & 7);
        int idx = r * 64 + slot * 4 + (lane & 3);  // uint units
        ((unsigned*)xhi)[idx] = (unsigned)h0 | ((unsigned)h1 << 16);
        ((unsigned*)xlo)[idx] = (unsigned)l0 | ((unsigned)l1 << 16);
    }
    __shared__ float sh[4][128];
    sh[w][lane * 2] = s0; sh[w][lane * 2 + 1] = s1;
    __syncthreads();
    if (t < 128) atomicAdd(&sums[t], sh[0][t] + sh[1][t] + sh[2][t] + sh[3][t]);
    __syncthreads();
    sh[w][lane * 2] = q0; sh[w][lane * 2 + 1] = q1;
    __syncthreads();
    if (t < 128) atomicAdd(&sums[128 + t], sh[0][t] + sh[1][t] + sh[2][t] + sh[3][t]);
}

__global__ void k_bn_finalize(const float* __restrict__ sums,
                              const float* __restrict__ gamma,
                              const float* __restrict__ beta,
                              float* __restrict__ scale,
                              float* __restrict__ shift) {
    int t = threadIdx.x;  // 128 threads
    float mean = sums[t] * (1.0f / N_NODES);
    float var  = sums[128 + t] * (1.0f / N_NODES) - mean * mean;
    float sc = gamma[t] * rsqrtf(var + 1e-5f);
    scale[t] = sc;
    shift[t] = beta[t] - mean * sc;
}

// Fold BN affine into weights; split to bf16 hi/lo, pre-swizzled like x
__global__ __launch_bounds__(256) void k_prep_w(const float* __restrict__ w_l,
                                                const float* __restrict__ b_l,
                                                const float* __restrict__ w_r,
                                                const float* __restrict__ b_r,
                                                const float* __restrict__ scale,
                                                const float* __restrict__ shift,
                                                unsigned short* __restrict__ Whi,
                                                unsigned short* __restrict__ Wlo,
                                                float* __restrict__ bp) {
    const int t = threadIdx.x;
    const int lane = t & 63;
    const int o = blockIdx.x * 4 + (t >> 6);       // 0..511
    const float* wrow = (o < NHID) ? (w_l + (size_t)o * F_IN)
                                   : (w_r + (size_t)(o - NHID) * F_IN);
    float bo = (o < NHID) ? b_l[o] : b_r[o - NHID];
    float2 wv = *(const float2*)(wrow + lane * 2);
    float w0 = wv.x * scale[lane * 2], w1 = wv.y * scale[lane * 2 + 1];
    unsigned short h0 = f2bf(w0), h1 = f2bf(w1);
    unsigned short l0 = f2bf(w0 - bf2f(h0)), l1 = f2bf(w1 - bf2f(h1));
    int slot = (lane >> 2) ^ (o & 7);
    int idx = o * 64 + slot * 4 + (lane & 3);
    ((unsigned*)Whi)[idx] = (unsigned)h0 | ((unsigned)h1 << 16);
    ((unsigned*)Wlo)[idx] = (unsigned)l0 | ((unsigned)l1 << 16);
    float part = shift[lane * 2] * wv.x + shift[lane * 2 + 1] * wv.y;  // raw W for bias fold
    #pragma unroll
    for (int m = 1; m < 64; m <<= 1) part += __shfl_xor(part, m, 64);
    if (lane == 0) bp[o] = bo + part;
}

// ---------------------------------------------------------------- MFMA GEMM
// D = (Ahi+Alo)(Bhi+Blo) ~= Ahi*Bhi + Ahi*Blo + Alo*Bhi  (fp32 accumulate)
// BM=BN=128, K=128 single-shot. 512 threads = 8 waves (2M x 4N), wave tile 64x32.
__global__ __launch_bounds__(512) void k_gemm_mfma(const unsigned short* __restrict__ xhi,
                                                   const unsigned short* __restrict__ xlo,
                                                   const unsigned short* __restrict__ Whi,
                                                   const unsigned short* __restrict__ Wlo,
                                                   const float* __restrict__ bp,
                                                   unsigned short* __restrict__ xs_bf,
                                                   unsigned short* __restrict__ xd_bf) {
    __shared__ __align__(16) char lds[131072];     // Ahi|Alo|Bhi|Blo, 32KB each
    const int t = threadIdx.x;
    const int bid = blockIdx.x;                    // 2048
    // XCD-partition: xcd = bid&7 owns M-chunk: A stays in its L2
    const int mb = (bid & 7) * 64 + ((bid >> 3) >> 2);   // 0..511
    const int nb = (bid >> 3) & 3;                 // 0..3
    const int m0 = mb * 128, n0 = nb * 128;
    {
        const uint4* srcs[4] = {
            (const uint4*)(xhi + (size_t)m0 * 128),
            (const uint4*)(xlo + (size_t)m0 * 128),
            (const uint4*)(Whi + (size_t)n0 * 128),
            (const uint4*)(Wlo + (size_t)n0 * 128)};
        #pragma unroll
        for (int c = 0; c < 4; ++c) {
            uint4* dst = (uint4*)(lds + c * 32768);
            #pragma unroll
            for (int q = 0; q < 4; ++q) {
                int i = q * 512 + t;               // 16B units, 2048 per 32KB chunk
                dst[i] = srcs[c][i];
            }
        }
    }
    __syncthreads();
    const int wvi = t >> 6, lane = t & 63;
    const int wm = wvi >> 2, wn = wvi & 3;         // 2 x 4 wave grid
    const int lg = lane >> 4, lr = lane & 15;
    f32x4 acc[4][2] = {};                          // mi(4 x 16 rows), nj(2 x 16 cols)
    #pragma unroll
    for (int ks = 0; ks < 4; ++ks) {
        bf16x8 ah[4], al[4], bh[2], bl[2];
        #pragma unroll
        for (int mi = 0; mi < 4; ++mi) {
            int r = wm * 64 + mi * 16 + lr;
            int off = r * 256 + ((((ks << 2) + lg) ^ (r & 7)) << 4);
            ah[mi] = *(const bf16x8*)(lds + off);
            al[mi] = *(const bf16x8*)(lds + 32768 + off);
        }
        #pragma unroll
        for (int nj = 0; nj < 2; ++nj) {
            int r = wn * 32 + nj * 16 + lr;
            int off = r * 256 + ((((ks << 2) + lg) ^ (r & 7)) << 4);
            bh[nj] = *(const bf16x8*)(lds + 65536 + off);
            bl[nj] = *(const bf16x8*)(lds + 98304 + off);
        }
        #pragma unroll
        for (int mi = 0; mi < 4; ++mi)
            #pragma unroll
            for (int nj = 0; nj < 2; ++nj) {
                acc[mi][nj] = __builtin_amdgcn_mfma_f32_16x16x32_bf16(ah[mi], bh[nj], acc[mi][nj], 0, 0, 0);
                acc[mi][nj] = __builtin_amdgcn_mfma_f32_16x16x32_bf16(ah[mi], bl[nj], acc[mi][nj], 0, 0, 0);
                acc[mi][nj] = __builtin_amdgcn_mfma_f32_16x16x32_bf16(al[mi], bh[nj], acc[mi][nj], 0, 0, 0);
            }
    }
    // epilogue: +bias, bf16, store. n0<256 -> xs half, else xd half (block-uniform)
    unsigned short* outp = (n0 < NHID) ? xs_bf : xd_bf;
    const int ncol0 = n0 & 255;
    #pragma unroll
    for (int nj = 0; nj < 2; ++nj) {
        int nc = wn * 32 + nj * 16 + lr;           // 0..127 within block
        float bcol = bp[n0 + nc];
        #pragma unroll
        for (int mi = 0; mi < 4; ++mi) {
            #pragma unroll
            for (int r = 0; r < 4; ++r) {
                int m = m0 + wm * 64 + mi * 16 + lg * 4 + r;   // C/D: col=lane&15, row=4*(lane>>4)+reg
                outp[(size_t)m * NHID + ncol0 + nc] = f2bf(acc[mi][nj][r] + bcol);
            }
        }
    }
}

// ---------------------------------------------------------------- CSR build (hierarchical, few atomics)
__global__ __launch_bounds__(256) void k_coarse(const int* __restrict__ ei,
                                                int* __restrict__ ccnt,
                                                unsigned* __restrict__ cbuf) {
    __shared__ int cnt[NBUCK];
    __shared__ int base[NBUCK];
    const int t = threadIdx.x;
    for (int i = t; i < NBUCK; i += 256) cnt[i] = 0;
    __syncthreads();
    const int e0 = blockIdx.x * 8192;
    int myrank[32];
    #pragma unroll
    for (int k = 0; k < 32; ++k) {
        int d = ei[N_EDGES + e0 + k * 256 + t];
        myrank[k] = atomicAdd(&cnt[d >> 6], 1);
    }
    __syncthreads();
    for (int i = t; i < NBUCK; i += 256)
        base[i] = (i << 11) + atomicAdd(&ccnt[i], cnt[i]);
    __syncthreads();
    #pragma unroll
    for (int k = 0; k < 32; ++k) {
        int e = e0 + k * 256 + t;
        int s = ei[e];
        int d = ei[N_EDGES + e];
        unsigned pos = (unsigned)(base[d >> 6] + myrank[k]);
        if ((pos >> 11) == (unsigned)(d >> 6))         // overflow guard
            cbuf[pos] = (unsigned)s | ((unsigned)(d & 63) << 16);
    }
}

__global__ __launch_bounds__(256) void k_fineA(const unsigned* __restrict__ cbuf,
                                               const int* __restrict__ ccnt,
                                               int* __restrict__ counts) {
    __shared__ int nc[64];
    const int t = threadIdx.x;
    const int b = blockIdx.x;
    if (t < 64) nc[t] = 0;
    __syncthreads();
    const int cnt = min(ccnt[b], BCAP);
    const unsigned* p = cbuf + (size_t)b * BCAP;
    for (int e = t; e < cnt; e += 256)
        atomicAdd(&nc[(p[e] >> 16) & 63], 1);
    __syncthreads();
    if (t < 64) counts[b * 64 + t] = nc[t];
}

__global__ __launch_bounds__(256) void k_scan1(const int* __restrict__ counts,
                                               int* __restrict__ row_start,
                                               int* __restrict__ blocksums) {
    __shared__ int sh[256];
    int t = threadIdx.x;
    int i = blockIdx.x * 256 + t;
    int v = counts[i];
    sh[t] = v;
    __syncthreads();
    for (int off = 1; off < 256; off <<= 1) {
        int add = (t >= off) ? sh[t - off] : 0;
        __syncthreads();
        sh[t] += add;
        __syncthreads();
    }
    row_start[i] = sh[t] - v;
    if (t == 255) blocksums[blockIdx.x] = sh[255];
}

__global__ void k_scan2(int* __restrict__ blocksums) {
    __shared__ int sh[256];
    int t = threadIdx.x;
    int v = blocksums[t];
    sh[t] = v;
    __syncthreads();
    for (int off = 1; off < 256; off <<= 1) {
        int add = (t >= off) ? sh[t - off] : 0;
        __syncthreads();
        sh[t] += add;
        __syncthreads();
    }
    blocksums[t] = sh[t] - v;
}

__global__ __launch_bounds__(256) void k_scan3(int* __restrict__ row_start,
                                               const int* __restrict__ blocksums) {
    int i = blockIdx.x * 256 + threadIdx.x;
    row_start[i] += blocksums[blockIdx.x];
}

__global__ __launch_bounds__(256) void k_fineB(const unsigned* __restrict__ cbuf,
                                               const int* __restrict__ ccnt,
                                               const int* __restrict__ row_start,
                                               int* __restrict__ csr) {
    __shared__ int rs[64];
    __shared__ int cur[64];
    const int t = threadIdx.x;
    const int b = blockIdx.x;
    if (t < 64) { rs[t] = row_start[b * 64 + t]; cur[t] = 0; }
    __syncthreads();
    const int cnt = min(ccnt[b], BCAP);
    const unsigned* p = cbuf + (size_t)b * BCAP;
    for (int e = t; e < cnt; e += 256) {
        unsigned w2 = p[e];
        int d = (w2 >> 16) & 63;
        int r = atomicAdd(&cur[d], 1);
        csr[rs[d] + r] = (int)(w2 & 0xffffu);
    }
}

// ---------------------------------------------------------------- aggregation
// one wave per dst node; 16 lanes per edge -> 4 edges per wave-step.
// lane: g = lane>>4 (edge slot), q = lane&15 (owns cols [16q,16q+16), head = q>>2).
// leaky_relu(v,0.2) = 0.6v + 0.4|v|  ->  logit = 0.6*dot(att,v) + 0.4*dot(att,|v|)
// 4 independent online-softmax states (one per group), merged exactly at the end.
__global__ __launch_bounds__(256) void k_aggregate(const unsigned short* __restrict__ xs_bf,
                                                   const unsigned short* __restrict__ xd_bf,
                                                   const int* __restrict__ row_start,
                                                   const int* __restrict__ counts,
                                                   const int* __restrict__ csr,
                                                   const float* __restrict__ att,
                                                   const float* __restrict__ bias,
                                                   float* __restrict__ out) {
    const int t = threadIdx.x;
    const int lane = t & 63;
    const int node = blockIdx.x * 4 + (t >> 6);
    const int g = lane >> 4;
    const int q = lane & 15;
    const char* xs_base = (const char*)xs_bf;

    // per-lane constants: att and xd for cols [16q, 16q+16)
    f32x2 attp[8], xdp[8];
    {
        const f32x2* ap = (const f32x2*)(att + q * 16);
        #pragma unroll
        for (int k = 0; k < 8; ++k) attp[k] = ap[k];
        const uint4* xr = (const uint4*)(xd_bf + (size_t)node * NHID + q * 16);
        uint4 xw0 = xr[0], xw1 = xr[1];
        xdp[0] = upk(xw0.x); xdp[1] = upk(xw0.y); xdp[2] = upk(xw0.z); xdp[3] = upk(xw0.w);
        xdp[4] = upk(xw1.x); xdp[5] = upk(xw1.y); xdp[6] = upk(xw1.z); xdp[7] = upk(xw1.w);
    }

    const int start = row_start[node];
    const int deg = counts[node];
    const int total = deg + 1;               // + self loop
    float m = -1e30f, s = 0.f;
    f32x2 acc[8] = {};

    for (int base0 = 0; base0 < total; base0 += 64) {
        const int rem = total - base0;
        const int cnt = rem < 64 ? rem : 64;
        int idx = node;                       // items in [deg,total) = self loop; pads too
        if (lane < cnt && base0 + lane < deg)
            idx = csr[start + base0 + lane];
        int src = __shfl(idx, g, 64);
        const char* p0 = xs_base + (((unsigned)src << 9) | ((unsigned)q << 5));
        uint4 c0 = *(const uint4*)p0;
        uint4 c1 = *(const uint4*)(p0 + 16);
        for (int jj = 0; jj < cnt; jj += 4) {
            uint4 u0 = c0, u1 = c1;
            if (jj + 4 < cnt) {               // prefetch next 4 items
                int sn = __shfl(idx, jj + 4 + g, 64);
                const char* pn = xs_base + (((unsigned)sn << 9) | ((unsigned)q << 5));
                c0 = *(const uint4*)pn;
                c1 = *(const uint4*)(pn + 16);
            }
            f32x2 x0 = upk(u0.x), x1 = upk(u0.y), x2 = upk(u0.z), x3 = upk(u0.w);
            f32x2 x4 = upk(u1.x), x5 = upk(u1.y), x6 = upk(u1.z), x7 = upk(u1.w);
            f32x2 dA = {0.f, 0.f}, dB = {0.f, 0.f};
            #define CH(k, xv) { f32x2 sv = xv + xdp[k]; f32x2 av; \
                av.x = fabsf(sv.x); av.y = fabsf(sv.y); \
                dA += attp[k] * sv; dB += attp[k] * av; }
            CH(0, x0) CH(1, x1) CH(2, x2) CH(3, x3)
            CH(4, x4) CH(5, x5) CH(6, x6) CH(7, x7)
            #undef CH
            float d = 0.6f * (dA.x + dA.y) + 0.4f * (dB.x + dB.y);
            d += __shfl_xor(d, 1, 64);
            d += __shfl_xor(d, 2, 64);        // per-head logit, replicated in quad
            if (base0 + jj + g >= total) d = -1e30f;   // pad item -> weight 0 (after merge)
            if (d > m + 8.0f) {               // defer-max rescale
                float f = __expf(m - d);
                s *= f;
                #pragma unroll
                for (int k = 0; k < 8; ++k) acc[k] *= f;
                m = d;
            }
            float p = __expf(d - m);
            s += p;
            f32x2 p2 = {p, p};
            acc[0] += p2 * x0; acc[1] += p2 * x1; acc[2] += p2 * x2; acc[3] += p2 * x3;
            acc[4] += p2 * x4; acc[5] += p2 * x5; acc[6] += p2 * x6; acc[7] += p2 * x7;
        }
    }

    // merge the 4 group states (all-pad groups have m=-1e30 -> f=0 exactly)
    float M = fmaxf(m, __shfl_xor(m, 16, 64));
    M = fmaxf(M, __shfl_xor(M, 32, 64));
    float f = __expf(m - M);
    float sf = s * f;
    sf += __shfl_xor(sf, 16, 64);
    sf += __shfl_xor(sf, 32, 64);
    float w = f / sf;                          // fold normalization into the merge scale
    f32x2 w2 = {w, w};
    #pragma unroll
    for (int k = 0; k < 8; ++k) {
        acc[k] *= w2;
        acc[k].x += __shfl_xor(acc[k].x, 16, 64);
        acc[k].x += __shfl_xor(acc[k].x, 32, 64);
        acc[k].y += __shfl_xor(acc[k].y, 16, 64);
        acc[k].y += __shfl_xor(acc[k].y, 32, 64);
        // head mean: heads of hid-block (q&3) live at q, q^4, q^8
        acc[k].x += __shfl_xor(acc[k].x, 4, 64);
        acc[k].x += __shfl_xor(acc[k].x, 8, 64);
        acc[k].y += __shfl_xor(acc[k].y, 4, 64);
        acc[k].y += __shfl_xor(acc[k].y, 8, 64);
    }
    if (g == 0 && q < 4) {                     // lane q holds hid block q (16 values)
        const f32x2* bp2 = (const f32x2*)(bias + q * 16);
        float o[16];
        #pragma unroll
        for (int k = 0; k < 8; ++k) {
            f32x2 b2 = bp2[k];
            float vx = acc[k].x * 0.25f + b2.x;
            float vy = acc[k].y * 0.25f + b2.y;
            o[2 * k]     = (vx > 0.f) ? vx : expm1f(vx);
            o[2 * k + 1] = (vy > 0.f) ? vy : expm1f(vy);
        }
        float* op = out + (size_t)node * HID + q * 16;
        #pragma unroll
        for (int v4 = 0; v4 < 4; ++v4)
            *(float4*)(op + v4 * 4) = *(float4*)(o + v4 * 4);
    }
}

// ---------------------------------------------------------------- launch
extern "C" void kernel_launch(void* const* d_in, const int* in_sizes, int n_in,
                              void* d_out, int out_size, void* d_ws, size_t ws_size,
                              hipStream_t stream) {
    const float* x     = (const float*)d_in[0];
    const int*   ei    = (const int*)d_in[1];
    const float* gamma = (const float*)d_in[4];
    const float* beta  = (const float*)d_in[5];
    const float* w_l   = (const float*)d_in[6];
    const float* b_l   = (const float*)d_in[7];
    const float* w_r   = (const float*)d_in[8];
    const float* b_r   = (const float*)d_in[9];
    const float* att   = (const float*)d_in[10];
    const float* bias  = (const float*)d_in[11];
    float* out = (float*)d_out;

    char* ws = (char*)d_ws;
    unsigned short* xs_bf = (unsigned short*)ws;                        // 32 MB
    unsigned short* xd_bf = xs_bf + (size_t)N_NODES * NHID;             // 32 MB
    unsigned short* xhi   = xd_bf + (size_t)N_NODES * NHID;             // 16 MB
    unsigned short* xlo   = xhi + (size_t)N_NODES * F_IN;               // 16 MB
    unsigned short* Whi   = xlo + (size_t)N_NODES * F_IN;               // 128 KB
    unsigned short* Wlo   = Whi + 512 * F_IN;                           // 128 KB
    float* bp    = (float*)(Wlo + 512 * F_IN);                          // 512
    float* scale = bp + 512;                                            // 128
    float* shift = scale + 128;                                         // 128
    float* sums  = shift + 128;                                         // 256  (memset from here)
    int* counts    = (int*)(sums + 256);                                // 65536
    int* ccnt      = counts + N_NODES;                                  // 1024 (memset to here)
    int* row_start = ccnt + NBUCK;                                      // 65536
    int* blocksums = row_start + N_NODES;                               // 256
    int* csr       = blocksums + 256;                                   // 1048576
    unsigned* cbuf = (unsigned*)(csr + N_EDGES);                        // 8 MB

    hipMemsetAsync(sums, 0, (256 + N_NODES + NBUCK) * sizeof(float), stream);

    k_bn_stats<<<256, 256, 0, stream>>>(x, sums, xhi, xlo);
    k_bn_finalize<<<1, 128, 0, stream>>>(sums, gamma, beta, scale, shift);
    k_prep_w<<<128, 256, 0, stream>>>(w_l, b_l, w_r, b_r, scale, shift, Whi, Wlo, bp);
    k_gemm_mfma<<<2048, 512, 0, stream>>>(xhi, xlo, Whi, Wlo, bp, xs_bf, xd_bf);

    k_coarse<<<N_EDGES / 8192, 256, 0, stream>>>(ei, ccnt, cbuf);
    k_fineA<<<NBUCK, 256, 0, stream>>>(cbuf, ccnt, counts);
    k_scan1<<<256, 256, 0, stream>>>(counts, row_start, blocksums);
    k_scan2<<<1, 256, 0, stream>>>(blocksums);
    k_scan3<<<256, 256, 0, stream>>>(row_start, blocksums);
    k_fineB<<<NBUCK, 256, 0, stream>>>(cbuf, ccnt, row_start, csr);

    k_aggregate<<<N_NODES / 4, 256, 0, stream>>>(xs_bf, xd_bf, row_start, counts, csr,
                                                 att, bias, out);
}

// Round 6
// 200.519 us; speedup vs baseline: 1.3012x; 1.3012x over previous
//
#include <hip/hip_runtime.h>
#include <hip/hip_bf16.h>

#define N_NODES 65536
#define N_EDGES 1048576
#define F_IN    128
#define HEADS   4
#define HID     64
#define NHID    256   // HEADS*HID
#define NBUCK   1024  // coarse buckets = dst>>6
#define BCAP    2048  // slots per bucket

typedef float fx4 __attribute__((ext_vector_type(4)));
typedef short bf16x8 __attribute__((ext_vector_type(8)));
typedef float f32x4 __attribute__((ext_vector_type(4)));

__device__ inline unsigned short f2bf(float f) {
    unsigned u = __float_as_uint(f);
    u += 0x7fff + ((u >> 16) & 1);          // round-to-nearest-even
    return (unsigned short)(u >> 16);
}
__device__ inline float bf2f(unsigned short h) {
    return __uint_as_float((unsigned)h << 16);
}
__device__ inline float bflo(unsigned w) { return __uint_as_float(w << 16); }
__device__ inline float bfhi(unsigned w) { return __uint_as_float(w & 0xffff0000u); }

// DPP-fused add: x + permute(x).  CTRL: 0xB1=xor1(quad_perm), 0x4E=xor2, 0x141=row_half_mirror
template <int CTRL>
__device__ inline float dpp_add(float x) {
    int y = __builtin_amdgcn_update_dpp(0, __float_as_int(x), CTRL, 0xf, 0xf, true);
    return x + __int_as_float(y);
}

// ---------------------------------------------------------------- BN stats + x -> bf16 hi/lo (pre-swizzled)
__global__ __launch_bounds__(256) void k_bn_stats(const float* __restrict__ x,
                                                  float* __restrict__ sums,
                                                  unsigned short* __restrict__ xhi,
                                                  unsigned short* __restrict__ xlo) {
    const int t = threadIdx.x;
    const int lane = t & 63;
    const int w = t >> 6;
    const int wid = blockIdx.x * 4 + w;            // 0..1023 global wave id
    float s0 = 0.f, s1 = 0.f, q0 = 0.f, q1 = 0.f;
    for (int i = 0; i < 64; ++i) {
        int r = wid + i * 1024;
        float2 v = *(const float2*)(x + (size_t)r * F_IN + lane * 2);
        s0 += v.x; q0 += v.x * v.x;
        s1 += v.y; q1 += v.y * v.y;
        unsigned short h0 = f2bf(v.x), h1 = f2bf(v.y);
        unsigned short l0 = f2bf(v.x - bf2f(h0)), l1 = f2bf(v.y - bf2f(h1));
        int slot = (lane >> 2) ^ (r & 7);
        int idx = r * 64 + slot * 4 + (lane & 3);  // uint units
        ((unsigned*)xhi)[idx] = (unsigned)h0 | ((unsigned)h1 << 16);
        ((unsigned*)xlo)[idx] = (unsigned)l0 | ((unsigned)l1 << 16);
    }
    __shared__ float sh[4][128];
    sh[w][lane * 2] = s0; sh[w][lane * 2 + 1] = s1;
    __syncthreads();
    if (t < 128) atomicAdd(&sums[t], sh[0][t] + sh[1][t] + sh[2][t] + sh[3][t]);
    __syncthreads();
    sh[w][lane * 2] = q0; sh[w][lane * 2 + 1] = q1;
    __syncthreads();
    if (t < 128) atomicAdd(&sums[128 + t], sh[0][t] + sh[1][t] + sh[2][t] + sh[3][t]);
}

__global__ void k_bn_finalize(const float* __restrict__ sums,
                              const float* __restrict__ gamma,
                              const float* __restrict__ beta,
                              const float* __restrict__ att,
                              float* __restrict__ scale,
                              float* __restrict__ shift,
                              float* __restrict__ att_l2e) {
    int t = threadIdx.x;  // 128 threads
    float mean = sums[t] * (1.0f / N_NODES);
    float var  = sums[128 + t] * (1.0f / N_NODES) - mean * mean;
    float sc = gamma[t] * rsqrtf(var + 1e-5f);
    scale[t] = sc;
    shift[t] = beta[t] - mean * sc;
    att_l2e[t]       = att[t]       * 1.44269504088896f;   // fold log2(e) into att
    att_l2e[t + 128] = att[t + 128] * 1.44269504088896f;
}

// Fold BN affine into weights; split to bf16 hi/lo, pre-swizzled like x
__global__ __launch_bounds__(256) void k_prep_w(const float* __restrict__ w_l,
                                                const float* __restrict__ b_l,
                                                const float* __restrict__ w_r,
                                                const float* __restrict__ b_r,
                                                const float* __restrict__ scale,
                                                const float* __restrict__ shift,
                                                unsigned short* __restrict__ Whi,
                                                unsigned short* __restrict__ Wlo,
                                                float* __restrict__ bp) {
    const int t = threadIdx.x;
    const int lane = t & 63;
    const int o = blockIdx.x * 4 + (t >> 6);       // 0..511
    const float* wrow = (o < NHID) ? (w_l + (size_t)o * F_IN)
                                   : (w_r + (size_t)(o - NHID) * F_IN);
    float bo = (o < NHID) ? b_l[o] : b_r[o - NHID];
    float2 wv = *(const float2*)(wrow + lane * 2);
    float w0 = wv.x * scale[lane * 2], w1 = wv.y * scale[lane * 2 + 1];
    unsigned short h0 = f2bf(w0), h1 = f2bf(w1);
    unsigned short l0 = f2bf(w0 - bf2f(h0)), l1 = f2bf(w1 - bf2f(h1));
    int slot = (lane >> 2) ^ (o & 7);
    int idx = o * 64 + slot * 4 + (lane & 3);
    ((unsigned*)Whi)[idx] = (unsigned)h0 | ((unsigned)h1 << 16);
    ((unsigned*)Wlo)[idx] = (unsigned)l0 | ((unsigned)l1 << 16);
    float part = shift[lane * 2] * wv.x + shift[lane * 2 + 1] * wv.y;  // raw W for bias fold
    #pragma unroll
    for (int m = 1; m < 64; m <<= 1) part += __shfl_xor(part, m, 64);
    if (lane == 0) bp[o] = bo + part;
}

// ---------------------------------------------------------------- MFMA GEMM
__global__ __launch_bounds__(512) void k_gemm_mfma(const unsigned short* __restrict__ xhi,
                                                   const unsigned short* __restrict__ xlo,
                                                   const unsigned short* __restrict__ Whi,
                                                   const unsigned short* __restrict__ Wlo,
                                                   const float* __restrict__ bp,
                                                   unsigned short* __restrict__ xs_bf,
                                                   unsigned short* __restrict__ xd_bf) {
    __shared__ __align__(16) char lds[131072];     // Ahi|Alo|Bhi|Blo, 32KB each
    const int t = threadIdx.x;
    const int bid = blockIdx.x;                    // 2048
    const int mb = (bid & 7) * 64 + ((bid >> 3) >> 2);   // XCD-partitioned M
    const int nb = (bid >> 3) & 3;
    const int m0 = mb * 128, n0 = nb * 128;
    {
        const uint4* srcs[4] = {
            (const uint4*)(xhi + (size_t)m0 * 128),
            (const uint4*)(xlo + (size_t)m0 * 128),
            (const uint4*)(Whi + (size_t)n0 * 128),
            (const uint4*)(Wlo + (size_t)n0 * 128)};
        #pragma unroll
        for (int c = 0; c < 4; ++c) {
            uint4* dst = (uint4*)(lds + c * 32768);
            #pragma unroll
            for (int q = 0; q < 4; ++q) {
                int i = q * 512 + t;
                dst[i] = srcs[c][i];
            }
        }
    }
    __syncthreads();
    const int wvi = t >> 6, lane = t & 63;
    const int wm = wvi >> 2, wn = wvi & 3;
    const int lg = lane >> 4, lr = lane & 15;
    f32x4 acc[4][2] = {};
    #pragma unroll
    for (int ks = 0; ks < 4; ++ks) {
        bf16x8 ah[4], al[4], bh[2], bl[2];
        #pragma unroll
        for (int mi = 0; mi < 4; ++mi) {
            int r = wm * 64 + mi * 16 + lr;
            int off = r * 256 + ((((ks << 2) + lg) ^ (r & 7)) << 4);
            ah[mi] = *(const bf16x8*)(lds + off);
            al[mi] = *(const bf16x8*)(lds + 32768 + off);
        }
        #pragma unroll
        for (int nj = 0; nj < 2; ++nj) {
            int r = wn * 32 + nj * 16 + lr;
            int off = r * 256 + ((((ks << 2) + lg) ^ (r & 7)) << 4);
            bh[nj] = *(const bf16x8*)(lds + 65536 + off);
            bl[nj] = *(const bf16x8*)(lds + 98304 + off);
        }
        #pragma unroll
        for (int mi = 0; mi < 4; ++mi)
            #pragma unroll
            for (int nj = 0; nj < 2; ++nj) {
                acc[mi][nj] = __builtin_amdgcn_mfma_f32_16x16x32_bf16(ah[mi], bh[nj], acc[mi][nj], 0, 0, 0);
                acc[mi][nj] = __builtin_amdgcn_mfma_f32_16x16x32_bf16(ah[mi], bl[nj], acc[mi][nj], 0, 0, 0);
                acc[mi][nj] = __builtin_amdgcn_mfma_f32_16x16x32_bf16(al[mi], bh[nj], acc[mi][nj], 0, 0, 0);
            }
    }
    unsigned short* outp = (n0 < NHID) ? xs_bf : xd_bf;
    const int ncol0 = n0 & 255;
    #pragma unroll
    for (int nj = 0; nj < 2; ++nj) {
        int nc = wn * 32 + nj * 16 + lr;
        float bcol = bp[n0 + nc];
        #pragma unroll
        for (int mi = 0; mi < 4; ++mi) {
            #pragma unroll
            for (int r = 0; r < 4; ++r) {
                int m = m0 + wm * 64 + mi * 16 + lg * 4 + r;
                outp[(size_t)m * NHID + ncol0 + nc] = f2bf(acc[mi][nj][r] + bcol);
            }
        }
    }
}

// ---------------------------------------------------------------- CSR build (hierarchical)
__global__ __launch_bounds__(256) void k_coarse(const int* __restrict__ ei,
                                                int* __restrict__ ccnt,
                                                unsigned* __restrict__ cbuf) {
    __shared__ int cnt[NBUCK];
    __shared__ int base[NBUCK];
    const int t = threadIdx.x;
    for (int i = t; i < NBUCK; i += 256) cnt[i] = 0;
    __syncthreads();
    const int e0 = blockIdx.x * 8192;
    int myrank[32];
    #pragma unroll
    for (int k = 0; k < 32; ++k) {
        int d = ei[N_EDGES + e0 + k * 256 + t];
        myrank[k] = atomicAdd(&cnt[d >> 6], 1);
    }
    __syncthreads();
    for (int i = t; i < NBUCK; i += 256)
        base[i] = (i << 11) + atomicAdd(&ccnt[i], cnt[i]);
    __syncthreads();
    #pragma unroll
    for (int k = 0; k < 32; ++k) {
        int e = e0 + k * 256 + t;
        int s = ei[e];
        int d = ei[N_EDGES + e];
        unsigned pos = (unsigned)(base[d >> 6] + myrank[k]);
        if ((pos >> 11) == (unsigned)(d >> 6))
            cbuf[pos] = (unsigned)s | ((unsigned)(d & 63) << 16);
    }
}

__global__ __launch_bounds__(256) void k_fineA(const unsigned* __restrict__ cbuf,
                                               const int* __restrict__ ccnt,
                                               int* __restrict__ counts) {
    __shared__ int nc[64];
    const int t = threadIdx.x;
    const int b = blockIdx.x;
    if (t < 64) nc[t] = 0;
    __syncthreads();
    const int cnt = min(ccnt[b], BCAP);
    const unsigned* p = cbuf + (size_t)b * BCAP;
    for (int e = t; e < cnt; e += 256)
        atomicAdd(&nc[(p[e] >> 16) & 63], 1);
    __syncthreads();
    if (t < 64) counts[b * 64 + t] = nc[t];
}

__global__ __launch_bounds__(256) void k_scan1(const int* __restrict__ counts,
                                               int* __restrict__ row_start,
                                               int* __restrict__ blocksums) {
    __shared__ int sh[256];
    int t = threadIdx.x;
    int i = blockIdx.x * 256 + t;
    int v = counts[i];
    sh[t] = v;
    __syncthreads();
    for (int off = 1; off < 256; off <<= 1) {
        int add = (t >= off) ? sh[t - off] : 0;
        __syncthreads();
        sh[t] += add;
        __syncthreads();
    }
    row_start[i] = sh[t] - v;
    if (t == 255) blocksums[blockIdx.x] = sh[255];
}

__global__ void k_scan2(int* __restrict__ blocksums) {
    __shared__ int sh[256];
    int t = threadIdx.x;
    int v = blocksums[t];
    sh[t] = v;
    __syncthreads();
    for (int off = 1; off < 256; off <<= 1) {
        int add = (t >= off) ? sh[t - off] : 0;
        __syncthreads();
        sh[t] += add;
        __syncthreads();
    }
    blocksums[t] = sh[t] - v;
}

__global__ __launch_bounds__(256) void k_scan3(int* __restrict__ row_start,
                                               const int* __restrict__ blocksums) {
    int i = blockIdx.x * 256 + threadIdx.x;
    row_start[i] += blocksums[blockIdx.x];
}

__global__ __launch_bounds__(256) void k_fineB(const unsigned* __restrict__ cbuf,
                                               const int* __restrict__ ccnt,
                                               const int* __restrict__ row_start,
                                               int* __restrict__ csr) {
    __shared__ int rs[64];
    __shared__ int cur[64];
    const int t = threadIdx.x;
    const int b = blockIdx.x;
    if (t < 64) { rs[t] = row_start[b * 64 + t]; cur[t] = 0; }
    __syncthreads();
    const int cnt = min(ccnt[b], BCAP);
    const unsigned* p = cbuf + (size_t)b * BCAP;
    for (int e = t; e < cnt; e += 256) {
        unsigned w2 = p[e];
        int d = (w2 >> 16) & 63;
        int r = atomicAdd(&cur[d], 1);
        csr[rs[d] + r] = (int)(w2 & 0xffffu);
    }
}

// ---------------------------------------------------------------- aggregation
// one wave per dst node; 32 lanes per edge -> 2 edges per wave-step.
// lane: h = lane>>5 (edge slot), q = lane&31 (owns cols [8q,8q+8), head = q>>3).
// Fixed-max softmax: logits of BN-normalized data are ~N(0,1); p = exp2(dot(att*log2e, lrelu))
// is overflow-safe without max subtraction -> no online-max state, no serial chain.
// Index stream is wave-uniform (readfirstlane) -> scalar loads on the scalar pipe.
// Accumulate p*sv; out = acc/s - xd at the end (since sum(alpha)=1).
__global__ __launch_bounds__(256) void k_aggregate(const unsigned short* __restrict__ xs_bf,
                                                   const unsigned short* __restrict__ xd_bf,
                                                   const int* __restrict__ row_start,
                                                   const int* __restrict__ counts,
                                                   const int* __restrict__ csr,
                                                   const float* __restrict__ att_l2e,
                                                   const float* __restrict__ bias,
                                                   float* __restrict__ out) {
    const int t = threadIdx.x;
    const int lane = t & 63;
    const int q = lane & 31;
    const int h = lane >> 5;
    const int node  = __builtin_amdgcn_readfirstlane(blockIdx.x * 4 + (t >> 6));
    const int start = __builtin_amdgcn_readfirstlane(row_start[node]);
    const int deg   = __builtin_amdgcn_readfirstlane(counts[node]);
    const int total = deg + 1;                     // item 0 = self loop, 1..deg = edges
    const int* csrp = csr + start;

    float att8[8], xd8[8];
    {
        const float4* ap = (const float4*)(att_l2e + q * 8);
        float4 a0 = ap[0], a1 = ap[1];
        att8[0] = a0.x; att8[1] = a0.y; att8[2] = a0.z; att8[3] = a0.w;
        att8[4] = a1.x; att8[5] = a1.y; att8[6] = a1.z; att8[7] = a1.w;
        uint4 xw = *(const uint4*)(xd_bf + (size_t)node * NHID + q * 8);
        xd8[0] = bflo(xw.x); xd8[1] = bfhi(xw.x);
        xd8[2] = bflo(xw.y); xd8[3] = bfhi(xw.y);
        xd8[4] = bflo(xw.z); xd8[5] = bfhi(xw.z);
        xd8[6] = bflo(xw.w); xd8[7] = bfhi(xw.w);
    }

    const char* xsb = (const char*)xs_bf;
    const unsigned voff = (unsigned)q * 16;
    float ssum = 0.f;
    float acc[8] = {};

    // first pair of sources; item 0 = self
    int sA = node;
    int it1 = (1 < total) ? 1 : 0;
    int sB = (it1 == 0) ? node : csrp[it1 - 1];
    int srcv = h ? sB : sA;
    uint4 u = *(const uint4*)(xsb + (((unsigned)srcv << 9) | voff));

    for (int j = 0; j < total; j += 2) {
        uint4 cur = u;
        int jn = j + 2;
        if (jn < total) {
            int nA = csrp[jn - 1];                 // jn>=2 -> always a csr edge
            int jB = (jn + 1 < total) ? jn + 1 : jn;
            int nB = csrp[jB - 1];
            int nsrc = h ? nB : nA;
            u = *(const uint4*)(xsb + (((unsigned)nsrc << 9) | voff));
        }
        float c0 = bflo(cur.x), c1 = bfhi(cur.x);
        float c2 = bflo(cur.y), c3 = bfhi(cur.y);
        float c4 = bflo(cur.z), c5 = bfhi(cur.z);
        float c6 = bflo(cur.w), c7 = bfhi(cur.w);
        float sv0 = c0 + xd8[0], sv1 = c1 + xd8[1];
        float sv2 = c2 + xd8[2], sv3 = c3 + xd8[3];
        float sv4 = c4 + xd8[4], sv5 = c5 + xd8[5];
        float sv6 = c6 + xd8[6], sv7 = c7 + xd8[7];
        float l0 = fmaxf(sv0, 0.2f * sv0), l1 = fmaxf(sv1, 0.2f * sv1);
        float l2 = fmaxf(sv2, 0.2f * sv2), l3 = fmaxf(sv3, 0.2f * sv3);
        float l4 = fmaxf(sv4, 0.2f * sv4), l5 = fmaxf(sv5, 0.2f * sv5);
        float l6 = fmaxf(sv6, 0.2f * sv6), l7 = fmaxf(sv7, 0.2f * sv7);
        float d = att8[0] * l0;
        d = fmaf(att8[1], l1, d); d = fmaf(att8[2], l2, d);
        d = fmaf(att8[3], l3, d); d = fmaf(att8[4], l4, d);
        d = fmaf(att8[5], l5, d); d = fmaf(att8[6], l6, d);
        d = fmaf(att8[7], l7, d);
        d = dpp_add<0xB1>(d);                      // xor 1
        d = dpp_add<0x4E>(d);                      // xor 2
        d = dpp_add<0x141>(d);                     // row_half_mirror: 8-lane head sum
        if (j + h >= total) d = -1e30f;            // odd-tail kill -> p = 0 exactly
        float p = __builtin_amdgcn_exp2f(d);
        ssum += p;
        acc[0] = fmaf(p, sv0, acc[0]); acc[1] = fmaf(p, sv1, acc[1]);
        acc[2] = fmaf(p, sv2, acc[2]); acc[3] = fmaf(p, sv3, acc[3]);
        acc[4] = fmaf(p, sv4, acc[4]); acc[5] = fmaf(p, sv5, acc[5]);
        acc[6] = fmaf(p, sv6, acc[6]); acc[7] = fmaf(p, sv7, acc[7]);
    }

    // merge the two halves
    ssum += __shfl_xor(ssum, 32, 64);
    #pragma unroll
    for (int k = 0; k < 8; ++k) acc[k] += __shfl_xor(acc[k], 32, 64);
    float inv = __builtin_amdgcn_rcpf(ssum);
    float r[8];
    #pragma unroll
    for (int k = 0; k < 8; ++k) r[k] = fmaf(acc[k], inv, -xd8[k]);
    // head mean over lanes q, q^8, q^16, q^24
    #pragma unroll
    for (int k = 0; k < 8; ++k) {
        r[k] += __shfl_xor(r[k], 8, 64);
        r[k] += __shfl_xor(r[k], 16, 64);
    }
    if (h == 0 && q < 8) {
        const float4* bp4 = (const float4*)(bias + q * 8);
        float4 b0 = bp4[0], b1 = bp4[1];
        float o[8];
        o[0] = r[0] * 0.25f + b0.x; o[1] = r[1] * 0.25f + b0.y;
        o[2] = r[2] * 0.25f + b0.z; o[3] = r[3] * 0.25f + b0.w;
        o[4] = r[4] * 0.25f + b1.x; o[5] = r[5] * 0.25f + b1.y;
        o[6] = r[6] * 0.25f + b1.z; o[7] = r[7] * 0.25f + b1.w;
        #pragma unroll
        for (int k = 0; k < 8; ++k) o[k] = (o[k] > 0.f) ? o[k] : expm1f(o[k]);
        float* op = out + (size_t)node * HID + q * 8;
        *(float4*)op       = {o[0], o[1], o[2], o[3]};
        *(float4*)(op + 4) = {o[4], o[5], o[6], o[7]};
    }
}

// ---------------------------------------------------------------- launch
extern "C" void kernel_launch(void* const* d_in, const int* in_sizes, int n_in,
                              void* d_out, int out_size, void* d_ws, size_t ws_size,
                              hipStream_t stream) {
    const float* x     = (const float*)d_in[0];
    const int*   ei    = (const int*)d_in[1];
    const float* gamma = (const float*)d_in[4];
    const float* beta  = (const float*)d_in[5];
    const float* w_l   = (const float*)d_in[6];
    const float* b_l   = (const float*)d_in[7];
    const float* w_r   = (const float*)d_in[8];
    const float* b_r   = (const float*)d_in[9];
    const float* att   = (const float*)d_in[10];
    const float* bias  = (const float*)d_in[11];
    float* out = (float*)d_out;

    char* ws = (char*)d_ws;
    unsigned short* xs_bf = (unsigned short*)ws;                        // 32 MB
    unsigned short* xd_bf = xs_bf + (size_t)N_NODES * NHID;             // 32 MB
    unsigned short* xhi   = xd_bf + (size_t)N_NODES * NHID;             // 16 MB
    unsigned short* xlo   = xhi + (size_t)N_NODES * F_IN;               // 16 MB
    unsigned short* Whi   = xlo + (size_t)N_NODES * F_IN;               // 128 KB
    unsigned short* Wlo   = Whi + 512 * F_IN;                           // 128 KB
    float* bp      = (float*)(Wlo + 512 * F_IN);                        // 512
    float* scale   = bp + 512;                                          // 128
    float* shift   = scale + 128;                                       // 128
    float* att_l2e = shift + 128;                                       // 256
    float* sums    = att_l2e + 256;                                     // 256  (memset from here)
    int* counts    = (int*)(sums + 256);                                // 65536
    int* ccnt      = counts + N_NODES;                                  // 1024 (memset to here)
    int* row_start = ccnt + NBUCK;                                      // 65536
    int* blocksums = row_start + N_NODES;                               // 256
    int* csr       = blocksums + 256;                                   // 1048576
    unsigned* cbuf = (unsigned*)(csr + N_EDGES);                        // 8 MB

    (void)hipMemsetAsync(sums, 0, (256 + N_NODES + NBUCK) * sizeof(float), stream);

    k_bn_stats<<<256, 256, 0, stream>>>(x, sums, xhi, xlo);
    k_bn_finalize<<<1, 128, 0, stream>>>(sums, gamma, beta, att, scale, shift, att_l2e);
    k_prep_w<<<128, 256, 0, stream>>>(w_l, b_l, w_r, b_r, scale, shift, Whi, Wlo, bp);
    k_gemm_mfma<<<2048, 512, 0, stream>>>(xhi, xlo, Whi, Wlo, bp, xs_bf, xd_bf);

    k_coarse<<<N_EDGES / 8192, 256, 0, stream>>>(ei, ccnt, cbuf);
    k_fineA<<<NBUCK, 256, 0, stream>>>(cbuf, ccnt, counts);
    k_scan1<<<256, 256, 0, stream>>>(counts, row_start, blocksums);
    k_scan2<<<1, 256, 0, stream>>>(blocksums);
    k_scan3<<<256, 256, 0, stream>>>(row_start, blocksums);
    k_fineB<<<NBUCK, 256, 0, stream>>>(cbuf, ccnt, row_start, csr);

    k_aggregate<<<N_NODES / 4, 256, 0, stream>>>(xs_bf, xd_bf, row_start, counts, csr,
                                                 att_l2e, bias, out);
}

// Round 7
// 180.538 us; speedup vs baseline: 1.4453x; 1.1107x over previous
//
#include <hip/hip_runtime.h>
#include <hip/hip_bf16.h>

#define N_NODES 65536
#define N_EDGES 1048576
#define F_IN    128
#define HEADS   4
#define HID     64
#define NHID    256   // HEADS*HID
#define NBUCK   1024  // coarse buckets = dst>>6
#define BCAP    2048  // slots per bucket

typedef float fx4 __attribute__((ext_vector_type(4)));
typedef short bf16x8 __attribute__((ext_vector_type(8)));
typedef float f32x4 __attribute__((ext_vector_type(4)));

__device__ inline unsigned short f2bf(float f) {
    unsigned u = __float_as_uint(f);
    u += 0x7fff + ((u >> 16) & 1);          // round-to-nearest-even
    return (unsigned short)(u >> 16);
}
__device__ inline float bf2f(unsigned short h) {
    return __uint_as_float((unsigned)h << 16);
}
__device__ inline float bflo(unsigned w) { return __uint_as_float(w << 16); }
__device__ inline float bfhi(unsigned w) { return __uint_as_float(w & 0xffff0000u); }

// DPP-fused add: x + permute(x).  CTRL: 0xB1=xor1(quad_perm), 0x4E=xor2, 0x141=row_half_mirror
template <int CTRL>
__device__ inline float dpp_add(float x) {
    int y = __builtin_amdgcn_update_dpp(0, __float_as_int(x), CTRL, 0xf, 0xf, true);
    return x + __int_as_float(y);
}

// ---------------------------------------------------------------- BN stats + x -> bf16 hi (pre-swizzled)
__global__ __launch_bounds__(256) void k_bn_stats(const float* __restrict__ x,
                                                  float* __restrict__ sums,
                                                  unsigned short* __restrict__ xhi) {
    const int t = threadIdx.x;
    const int lane = t & 63;
    const int w = t >> 6;
    const int wid = blockIdx.x * 4 + w;            // 0..1023 global wave id
    float s0 = 0.f, s1 = 0.f, q0 = 0.f, q1 = 0.f;
    for (int i = 0; i < 64; ++i) {
        int r = wid + i * 1024;
        float2 v = *(const float2*)(x + (size_t)r * F_IN + lane * 2);
        s0 += v.x; q0 += v.x * v.x;
        s1 += v.y; q1 += v.y * v.y;
        unsigned short h0 = f2bf(v.x), h1 = f2bf(v.y);
        int slot = (lane >> 2) ^ (r & 7);
        int idx = r * 64 + slot * 4 + (lane & 3);  // uint units
        ((unsigned*)xhi)[idx] = (unsigned)h0 | ((unsigned)h1 << 16);
    }
    __shared__ float sh[4][128];
    sh[w][lane * 2] = s0; sh[w][lane * 2 + 1] = s1;
    __syncthreads();
    if (t < 128) atomicAdd(&sums[t], sh[0][t] + sh[1][t] + sh[2][t] + sh[3][t]);
    __syncthreads();
    sh[w][lane * 2] = q0; sh[w][lane * 2 + 1] = q1;
    __syncthreads();
    if (t < 128) atomicAdd(&sums[128 + t], sh[0][t] + sh[1][t] + sh[2][t] + sh[3][t]);
}

__global__ void k_bn_finalize(const float* __restrict__ sums,
                              const float* __restrict__ gamma,
                              const float* __restrict__ beta,
                              const float* __restrict__ att,
                              float* __restrict__ scale,
                              float* __restrict__ shift,
                              float* __restrict__ att_l2e) {
    int t = threadIdx.x;  // 128 threads
    float mean = sums[t] * (1.0f / N_NODES);
    float var  = sums[128 + t] * (1.0f / N_NODES) - mean * mean;
    float sc = gamma[t] * rsqrtf(var + 1e-5f);
    scale[t] = sc;
    shift[t] = beta[t] - mean * sc;
    att_l2e[t]       = att[t]       * 1.44269504088896f;   // fold log2(e) into att
    att_l2e[t + 128] = att[t + 128] * 1.44269504088896f;
}

// Fold BN affine into weights; split to bf16 hi/lo, pre-swizzled like x
__global__ __launch_bounds__(256) void k_prep_w(const float* __restrict__ w_l,
                                                const float* __restrict__ b_l,
                                                const float* __restrict__ w_r,
                                                const float* __restrict__ b_r,
                                                const float* __restrict__ scale,
                                                const float* __restrict__ shift,
                                                unsigned short* __restrict__ Whi,
                                                unsigned short* __restrict__ Wlo,
                                                float* __restrict__ bp) {
    const int t = threadIdx.x;
    const int lane = t & 63;
    const int o = blockIdx.x * 4 + (t >> 6);       // 0..511
    const float* wrow = (o < NHID) ? (w_l + (size_t)o * F_IN)
                                   : (w_r + (size_t)(o - NHID) * F_IN);
    float bo = (o < NHID) ? b_l[o] : b_r[o - NHID];
    float2 wv = *(const float2*)(wrow + lane * 2);
    float w0 = wv.x * scale[lane * 2], w1 = wv.y * scale[lane * 2 + 1];
    unsigned short h0 = f2bf(w0), h1 = f2bf(w1);
    unsigned short l0 = f2bf(w0 - bf2f(h0)), l1 = f2bf(w1 - bf2f(h1));
    int slot = (lane >> 2) ^ (o & 7);
    int idx = o * 64 + slot * 4 + (lane & 3);
    ((unsigned*)Whi)[idx] = (unsigned)h0 | ((unsigned)h1 << 16);
    ((unsigned*)Wlo)[idx] = (unsigned)l0 | ((unsigned)l1 << 16);
    float part = shift[lane * 2] * wv.x + shift[lane * 2 + 1] * wv.y;  // raw W for bias fold
    #pragma unroll
    for (int m = 1; m < 64; m <<= 1) part += __shfl_xor(part, m, 64);
    if (lane == 0) bp[o] = bo + part;
}

// ---------------------------------------------------------------- MFMA GEMM
// D = Ahi*(Bhi+Blo)  (x bf16-rounded, W split; fp32 accumulate)
// BM=BN=128, K=128 single-shot. 512 threads = 8 waves (2M x 4N), wave tile 64x32.
__global__ __launch_bounds__(512) void k_gemm_mfma(const unsigned short* __restrict__ xhi,
                                                   const unsigned short* __restrict__ Whi,
                                                   const unsigned short* __restrict__ Wlo,
                                                   const float* __restrict__ bp,
                                                   unsigned short* __restrict__ xs_bf,
                                                   unsigned short* __restrict__ xd_bf) {
    __shared__ __align__(16) char lds[98304];      // Ahi|Bhi|Blo, 32KB each
    const int t = threadIdx.x;
    const int bid = blockIdx.x;                    // 2048
    const int mb = (bid & 7) * 64 + ((bid >> 3) >> 2);   // XCD-partitioned M
    const int nb = (bid >> 3) & 3;
    const int m0 = mb * 128, n0 = nb * 128;
    {
        const uint4* srcs[3] = {
            (const uint4*)(xhi + (size_t)m0 * 128),
            (const uint4*)(Whi + (size_t)n0 * 128),
            (const uint4*)(Wlo + (size_t)n0 * 128)};
        #pragma unroll
        for (int c = 0; c < 3; ++c) {
            uint4* dst = (uint4*)(lds + c * 32768);
            #pragma unroll
            for (int q = 0; q < 4; ++q) {
                int i = q * 512 + t;
                dst[i] = srcs[c][i];
            }
        }
    }
    __syncthreads();
    const int wvi = t >> 6, lane = t & 63;
    const int wm = wvi >> 2, wn = wvi & 3;
    const int lg = lane >> 4, lr = lane & 15;
    f32x4 acc[4][2] = {};
    #pragma unroll
    for (int ks = 0; ks < 4; ++ks) {
        bf16x8 ah[4], bh[2], bl[2];
        #pragma unroll
        for (int mi = 0; mi < 4; ++mi) {
            int r = wm * 64 + mi * 16 + lr;
            int off = r * 256 + ((((ks << 2) + lg) ^ (r & 7)) << 4);
            ah[mi] = *(const bf16x8*)(lds + off);
        }
        #pragma unroll
        for (int nj = 0; nj < 2; ++nj) {
            int r = wn * 32 + nj * 16 + lr;
            int off = r * 256 + ((((ks << 2) + lg) ^ (r & 7)) << 4);
            bh[nj] = *(const bf16x8*)(lds + 32768 + off);
            bl[nj] = *(const bf16x8*)(lds + 65536 + off);
        }
        #pragma unroll
        for (int mi = 0; mi < 4; ++mi)
            #pragma unroll
            for (int nj = 0; nj < 2; ++nj) {
                acc[mi][nj] = __builtin_amdgcn_mfma_f32_16x16x32_bf16(ah[mi], bh[nj], acc[mi][nj], 0, 0, 0);
                acc[mi][nj] = __builtin_amdgcn_mfma_f32_16x16x32_bf16(ah[mi], bl[nj], acc[mi][nj], 0, 0, 0);
            }
    }
    unsigned short* outp = (n0 < NHID) ? xs_bf : xd_bf;
    const int ncol0 = n0 & 255;
    #pragma unroll
    for (int nj = 0; nj < 2; ++nj) {
        int nc = wn * 32 + nj * 16 + lr;
        float bcol = bp[n0 + nc];
        #pragma unroll
        for (int mi = 0; mi < 4; ++mi) {
            #pragma unroll
            for (int r = 0; r < 4; ++r) {
                int m = m0 + wm * 64 + mi * 16 + lg * 4 + r;
                outp[(size_t)m * NHID + ncol0 + nc] = f2bf(acc[mi][nj][r] + bcol);
            }
        }
    }
}

// ---------------------------------------------------------------- CSR build (hierarchical)
__global__ __launch_bounds__(256) void k_coarse(const int* __restrict__ ei,
                                                int* __restrict__ ccnt,
                                                unsigned* __restrict__ cbuf) {
    __shared__ int cnt[NBUCK];
    __shared__ int base[NBUCK];
    const int t = threadIdx.x;
    for (int i = t; i < NBUCK; i += 256) cnt[i] = 0;
    __syncthreads();
    const int e0 = blockIdx.x * 4096;
    int myrank[16];
    #pragma unroll
    for (int k = 0; k < 16; ++k) {
        int d = ei[N_EDGES + e0 + k * 256 + t];
        myrank[k] = atomicAdd(&cnt[d >> 6], 1);
    }
    __syncthreads();
    for (int i = t; i < NBUCK; i += 256)
        base[i] = (i << 11) + atomicAdd(&ccnt[i], cnt[i]);
    __syncthreads();
    #pragma unroll
    for (int k = 0; k < 16; ++k) {
        int e = e0 + k * 256 + t;
        int s = ei[e];
        int d = ei[N_EDGES + e];
        unsigned pos = (unsigned)(base[d >> 6] + myrank[k]);
        if ((pos >> 11) == (unsigned)(d >> 6))
            cbuf[pos] = (unsigned)s | ((unsigned)(d & 63) << 16);
    }
}

__global__ __launch_bounds__(256) void k_fineA(const unsigned* __restrict__ cbuf,
                                               const int* __restrict__ ccnt,
                                               int* __restrict__ counts) {
    __shared__ int nc[64];
    const int t = threadIdx.x;
    const int b = blockIdx.x;
    if (t < 64) nc[t] = 0;
    __syncthreads();
    const int cnt = min(ccnt[b], BCAP);
    const unsigned* p = cbuf + (size_t)b * BCAP;
    for (int e = t; e < cnt; e += 256)
        atomicAdd(&nc[(p[e] >> 16) & 63], 1);
    __syncthreads();
    if (t < 64) counts[b * 64 + t] = nc[t];
}

__global__ __launch_bounds__(256) void k_scan1(const int* __restrict__ counts,
                                               int* __restrict__ row_start,
                                               int* __restrict__ blocksums) {
    __shared__ int sh[256];
    int t = threadIdx.x;
    int i = blockIdx.x * 256 + t;
    int v = counts[i];
    sh[t] = v;
    __syncthreads();
    for (int off = 1; off < 256; off <<= 1) {
        int add = (t >= off) ? sh[t - off] : 0;
        __syncthreads();
        sh[t] += add;
        __syncthreads();
    }
    row_start[i] = sh[t] - v;
    if (t == 255) blocksums[blockIdx.x] = sh[255];
}

__global__ void k_scan2(int* __restrict__ blocksums) {
    __shared__ int sh[256];
    int t = threadIdx.x;
    int v = blocksums[t];
    sh[t] = v;
    __syncthreads();
    for (int off = 1; off < 256; off <<= 1) {
        int add = (t >= off) ? sh[t - off] : 0;
        __syncthreads();
        sh[t] += add;
        __syncthreads();
    }
    blocksums[t] = sh[t] - v;
}

__global__ __launch_bounds__(256) void k_scan3(int* __restrict__ row_start,
                                               const int* __restrict__ blocksums) {
    int i = blockIdx.x * 256 + threadIdx.x;
    row_start[i] += blocksums[blockIdx.x];
}

__global__ __launch_bounds__(256) void k_fineB(const unsigned* __restrict__ cbuf,
                                               const int* __restrict__ ccnt,
                                               const int* __restrict__ row_start,
                                               int* __restrict__ csr) {
    __shared__ int rs[64];
    __shared__ int cur[64];
    const int t = threadIdx.x;
    const int b = blockIdx.x;
    if (t < 64) { rs[t] = row_start[b * 64 + t]; cur[t] = 0; }
    __syncthreads();
    const int cnt = min(ccnt[b], BCAP);
    const unsigned* p = cbuf + (size_t)b * BCAP;
    for (int e = t; e < cnt; e += 256) {
        unsigned w2 = p[e];
        int d = (w2 >> 16) & 63;
        int r = atomicAdd(&cur[d], 1);
        csr[rs[d] + r] = (int)(w2 & 0xffffu);
    }
}

// ---------------------------------------------------------------- aggregation
// one wave per dst node; 32 lanes per edge -> 2 edges per wave-step.
// lane: h = lane>>5 (edge slot), q = lane&31 (owns cols [8q,8q+8), head = q>>3).
// Fixed-max softmax (logits ~N(0,1), exp2 safe without max subtraction).
// __launch_bounds__(256,4): 128-VGPR budget -- R6's 24-VGPR allocation spilled
// the ~40 live values through AGPRs (v_accvgpr VALU traffic = 10x instr bloat).
__global__ __launch_bounds__(256, 4) void k_aggregate(const unsigned short* __restrict__ xs_bf,
                                                      const unsigned short* __restrict__ xd_bf,
                                                      const int* __restrict__ row_start,
                                                      const int* __restrict__ counts,
                                                      const int* __restrict__ csr,
                                                      const float* __restrict__ att_l2e,
                                                      const float* __restrict__ bias,
                                                      float* __restrict__ out) {
    const int t = threadIdx.x;
    const int lane = t & 63;
    const int q = lane & 31;
    const int h = lane >> 5;
    const int node  = __builtin_amdgcn_readfirstlane(blockIdx.x * 4 + (t >> 6));
    const int start = __builtin_amdgcn_readfirstlane(row_start[node]);
    const int deg   = __builtin_amdgcn_readfirstlane(counts[node]);
    const int total = deg + 1;                     // item 0 = self loop, 1..deg = edges
    const int* csrp = csr + start;

    float att8[8], xd8[8];
    {
        const float4* ap = (const float4*)(att_l2e + q * 8);
        float4 a0 = ap[0], a1 = ap[1];
        att8[0] = a0.x; att8[1] = a0.y; att8[2] = a0.z; att8[3] = a0.w;
        att8[4] = a1.x; att8[5] = a1.y; att8[6] = a1.z; att8[7] = a1.w;
        uint4 xw = *(const uint4*)(xd_bf + (size_t)node * NHID + q * 8);
        xd8[0] = bflo(xw.x); xd8[1] = bfhi(xw.x);
        xd8[2] = bflo(xw.y); xd8[3] = bfhi(xw.y);
        xd8[4] = bflo(xw.z); xd8[5] = bfhi(xw.z);
        xd8[6] = bflo(xw.w); xd8[7] = bfhi(xw.w);
    }

    const char* xsb = (const char*)xs_bf;
    const unsigned voff = (unsigned)q * 16;
    float ssum = 0.f;
    float acc[8] = {};

    // first pair of sources; item 0 = self
    int sA = node;
    int it1 = (1 < total) ? 1 : 0;
    int sB = (it1 == 0) ? node : csrp[it1 - 1];
    int srcv = h ? sB : sA;
    uint4 u = *(const uint4*)(xsb + (((unsigned)srcv << 9) | voff));

    for (int j = 0; j < total; j += 2) {
        uint4 cur = u;
        int jn = j + 2;
        if (jn < total) {
            int nA = csrp[jn - 1];                 // jn>=2 -> always a csr edge
            int jB = (jn + 1 < total) ? jn + 1 : jn;
            int nB = csrp[jB - 1];
            int nsrc = h ? nB : nA;
            u = *(const uint4*)(xsb + (((unsigned)nsrc << 9) | voff));
        }
        float c0 = bflo(cur.x), c1 = bfhi(cur.x);
        float c2 = bflo(cur.y), c3 = bfhi(cur.y);
        float c4 = bflo(cur.z), c5 = bfhi(cur.z);
        float c6 = bflo(cur.w), c7 = bfhi(cur.w);
        float sv0 = c0 + xd8[0], sv1 = c1 + xd8[1];
        float sv2 = c2 + xd8[2], sv3 = c3 + xd8[3];
        float sv4 = c4 + xd8[4], sv5 = c5 + xd8[5];
        float sv6 = c6 + xd8[6], sv7 = c7 + xd8[7];
        float l0 = fmaxf(sv0, 0.2f * sv0), l1 = fmaxf(sv1, 0.2f * sv1);
        float l2 = fmaxf(sv2, 0.2f * sv2), l3 = fmaxf(sv3, 0.2f * sv3);
        float l4 = fmaxf(sv4, 0.2f * sv4), l5 = fmaxf(sv5, 0.2f * sv5);
        float l6 = fmaxf(sv6, 0.2f * sv6), l7 = fmaxf(sv7, 0.2f * sv7);
        float d = att8[0] * l0;
        d = fmaf(att8[1], l1, d); d = fmaf(att8[2], l2, d);
        d = fmaf(att8[3], l3, d); d = fmaf(att8[4], l4, d);
        d = fmaf(att8[5], l5, d); d = fmaf(att8[6], l6, d);
        d = fmaf(att8[7], l7, d);
        d = dpp_add<0xB1>(d);                      // xor 1
        d = dpp_add<0x4E>(d);                      // xor 2
        d = dpp_add<0x141>(d);                     // row_half_mirror: 8-lane head sum
        if (j + h >= total) d = -1e30f;            // odd-tail kill -> p = 0 exactly
        float p = __builtin_amdgcn_exp2f(d);
        ssum += p;
        acc[0] = fmaf(p, sv0, acc[0]); acc[1] = fmaf(p, sv1, acc[1]);
        acc[2] = fmaf(p, sv2, acc[2]); acc[3] = fmaf(p, sv3, acc[3]);
        acc[4] = fmaf(p, sv4, acc[4]); acc[5] = fmaf(p, sv5, acc[5]);
        acc[6] = fmaf(p, sv6, acc[6]); acc[7] = fmaf(p, sv7, acc[7]);
    }

    // merge the two halves
    ssum += __shfl_xor(ssum, 32, 64);
    #pragma unroll
    for (int k = 0; k < 8; ++k) acc[k] += __shfl_xor(acc[k], 32, 64);
    float inv = __builtin_amdgcn_rcpf(ssum);
    float r[8];
    #pragma unroll
    for (int k = 0; k < 8; ++k) r[k] = fmaf(acc[k], inv, -xd8[k]);
    // head mean over lanes q, q^8, q^16, q^24
    #pragma unroll
    for (int k = 0; k < 8; ++k) {
        r[k] += __shfl_xor(r[k], 8, 64);
        r[k] += __shfl_xor(r[k], 16, 64);
    }
    if (h == 0 && q < 8) {
        const float4* bp4 = (const float4*)(bias + q * 8);
        float4 b0 = bp4[0], b1 = bp4[1];
        float o[8];
        o[0] = r[0] * 0.25f + b0.x; o[1] = r[1] * 0.25f + b0.y;
        o[2] = r[2] * 0.25f + b0.z; o[3] = r[3] * 0.25f + b0.w;
        o[4] = r[4] * 0.25f + b1.x; o[5] = r[5] * 0.25f + b1.y;
        o[6] = r[6] * 0.25f + b1.z; o[7] = r[7] * 0.25f + b1.w;
        #pragma unroll
        for (int k = 0; k < 8; ++k) o[k] = (o[k] > 0.f) ? o[k] : expm1f(o[k]);
        float* op = out + (size_t)node * HID + q * 8;
        *(float4*)op       = {o[0], o[1], o[2], o[3]};
        *(float4*)(op + 4) = {o[4], o[5], o[6], o[7]};
    }
}

// ---------------------------------------------------------------- launch
extern "C" void kernel_launch(void* const* d_in, const int* in_sizes, int n_in,
                              void* d_out, int out_size, void* d_ws, size_t ws_size,
                              hipStream_t stream) {
    const float* x     = (const float*)d_in[0];
    const int*   ei    = (const int*)d_in[1];
    const float* gamma = (const float*)d_in[4];
    const float* beta  = (const float*)d_in[5];
    const float* w_l   = (const float*)d_in[6];
    const float* b_l   = (const float*)d_in[7];
    const float* w_r   = (const float*)d_in[8];
    const float* b_r   = (const float*)d_in[9];
    const float* att   = (const float*)d_in[10];
    const float* bias  = (const float*)d_in[11];
    float* out = (float*)d_out;

    char* ws = (char*)d_ws;
    unsigned short* xs_bf = (unsigned short*)ws;                        // 32 MB
    unsigned short* xd_bf = xs_bf + (size_t)N_NODES * NHID;             // 32 MB
    unsigned short* xhi   = xd_bf + (size_t)N_NODES * NHID;             // 16 MB
    unsigned short* Whi   = xhi + (size_t)N_NODES * F_IN;               // 128 KB
    unsigned short* Wlo   = Whi + 512 * F_IN;                           // 128 KB
    float* bp      = (float*)(Wlo + 512 * F_IN);                        // 512
    float* scale   = bp + 512;                                          // 128
    float* shift   = scale + 128;                                       // 128
    float* att_l2e = shift + 128;                                       // 256
    float* sums    = att_l2e + 256;                                     // 256  (memset from here)
    int* counts    = (int*)(sums + 256);                                // 65536
    int* ccnt      = counts + N_NODES;                                  // 1024 (memset to here)
    int* row_start = ccnt + NBUCK;                                      // 65536
    int* blocksums = row_start + N_NODES;                               // 256
    int* csr       = blocksums + 256;                                   // 1048576
    unsigned* cbuf = (unsigned*)(csr + N_EDGES);                        // 8 MB

    (void)hipMemsetAsync(sums, 0, (256 + N_NODES + NBUCK) * sizeof(float), stream);

    k_bn_stats<<<256, 256, 0, stream>>>(x, sums, xhi);
    k_bn_finalize<<<1, 128, 0, stream>>>(sums, gamma, beta, att, scale, shift, att_l2e);
    k_prep_w<<<128, 256, 0, stream>>>(w_l, b_l, w_r, b_r, scale, shift, Whi, Wlo, bp);
    k_gemm_mfma<<<2048, 512, 0, stream>>>(xhi, Whi, Wlo, bp, xs_bf, xd_bf);

    k_coarse<<<N_EDGES / 4096, 256, 0, stream>>>(ei, ccnt, cbuf);
    k_fineA<<<NBUCK, 256, 0, stream>>>(cbuf, ccnt, counts);
    k_scan1<<<256, 256, 0, stream>>>(counts, row_start, blocksums);
    k_scan2<<<1, 256, 0, stream>>>(blocksums);
    k_scan3<<<256, 256, 0, stream>>>(row_start, blocksums);
    k_fineB<<<NBUCK, 256, 0, stream>>>(cbuf, ccnt, row_start, csr);

    k_aggregate<<<N_NODES / 4, 256, 0, stream>>>(xs_bf, xd_bf, row_start, counts, csr,
                                                 att_l2e, bias, out);
}